// Round 1
// baseline (298.865 us; speedup 1.0000x reference)
//
#include <hip/hip_runtime.h>
#include <hip/hip_bf16.h>
#include <math.h>

// DIN forward, MI355X. Shapes: B=32, N=256, L=50, DU=DI=32, DC=16, D=48.
// K1: per-(b,n) attention with algebraic factoring (K=192 -> K=48, layers 2+3 collapsed)
// K2: 128->200->80->1 MLP, 32 rows per block
// K3: masked softmax over N=256

#define NL 50
#define BN_TOT 8192   // B*N

__device__ __forceinline__ float relu_dot(float4 a, float4 qc, float4 w) {
    float hx = fmaxf(qc.x + a.x, 0.f);
    float hy = fmaxf(qc.y + a.y, 0.f);
    float hz = fmaxf(qc.z + a.z, 0.f);
    float hw = fmaxf(qc.w + a.w, 0.f);
    return fmaf(hx, w.x, fmaf(hy, w.y, fmaf(hz, w.z, hw * w.w)));
}

__global__ __launch_bounds__(256) void k1_attn(
    const float* __restrict__ emb_user,
    const float* __restrict__ emb_item,
    const float* __restrict__ emb_cate,
    const float* __restrict__ w1,   // [192][64]
    const float* __restrict__ b1,   // [64]
    const float* __restrict__ w2,   // [64][16]
    const float* __restrict__ b2,   // [16]
    const float* __restrict__ w3,   // [16]
    const float* __restrict__ b3,   // [1]
    const int* __restrict__ user,
    const int* __restrict__ items,
    const int* __restrict__ cates,
    const int* __restrict__ ii,
    const int* __restrict__ ic,
    float* __restrict__ feat)       // [8192][128]
{
    const int bn = blockIdx.x;
    const int t  = threadIdx.x;

    __shared__ float he[52][52];   // rows 50,51 zero-padded; stride 52 (16B-aligned float4 rows)
    __shared__ float q[48];
    __shared__ float u[32];
    __shared__ float Wq[48][64];
    __shared__ float qc[64];
    __shared__ float w23[64];
    __shared__ float score[50];
    __shared__ int   iml[50];
    __shared__ float c23s;

    // ---- phase 0: gathers ----
    if (t < 32)       q[t]      = emb_item[(size_t)items[bn] * 32 + t];
    else if (t < 48)  q[t]      = emb_cate[(size_t)cates[bn] * 16 + (t - 32)];
    else if (t < 80)  u[t - 48] = emb_user[(size_t)user[bn]  * 32 + (t - 48)];
    if (t >= 80 && t < 130) iml[t - 80] = ii[bn * NL + (t - 80)];

    for (int e = t; e < 52 * 48; e += 256) {
        int l = e / 48, k = e - l * 48;
        float v = 0.f;
        if (l < NL) {
            if (k < 32) v = emb_item[(size_t)ii[bn * NL + l] * 32 + k];
            else        v = emb_cate[(size_t)ic[bn * NL + l] * 16 + (k - 32)];
        }
        he[l][k] = v;
    }
    __syncthreads();

    // ---- phase 1: Wq, qc, w23, c23 ----
    for (int e = t; e < 48 * 64; e += 256) {
        int k = e >> 6, j = e & 63;
        Wq[k][j] = w1[(48 + k) * 64 + j] - w1[(96 + k) * 64 + j]
                 + q[k] * w1[(144 + k) * 64 + j];
    }
    if (t < 64) {
        float a = b1[t];
        #pragma unroll 4
        for (int k = 0; k < 48; ++k)
            a = fmaf(q[k], w1[k * 64 + t] + w1[(96 + k) * 64 + t], a);
        qc[t] = a;
        float s = 0.f;
        #pragma unroll
        for (int jj = 0; jj < 16; ++jj) s = fmaf(w2[t * 16 + jj], w3[jj], s);
        w23[t] = s;
    }
    if (t == 192) {
        float c = b3[0];
        #pragma unroll
        for (int jj = 0; jj < 16; ++jj) c = fmaf(b2[jj], w3[jj], c);
        c23s = c;
    }
    __syncthreads();

    // ---- phase 2: h1 = relu(qc + he@Wq); score = h1 . w23 + c23 ----
    // 208 threads: jg = t&15 covers 4 cols (j = jg*4..), lg = t>>4 covers 4 rows.
    if (t < 208) {
        const int jg = t & 15, lg = t >> 4;
        const int l0 = lg * 4;
        float4 a0 = {0,0,0,0}, a1 = a0, a2 = a0, a3 = a0;
        #pragma unroll 4
        for (int k = 0; k < 48; ++k) {
            float4 w = *(const float4*)&Wq[k][jg * 4];
            float h0 = he[l0 + 0][k];
            float h1 = he[l0 + 1][k];
            float h2 = he[l0 + 2][k];
            float h3 = he[l0 + 3][k];
            a0.x = fmaf(h0, w.x, a0.x); a0.y = fmaf(h0, w.y, a0.y);
            a0.z = fmaf(h0, w.z, a0.z); a0.w = fmaf(h0, w.w, a0.w);
            a1.x = fmaf(h1, w.x, a1.x); a1.y = fmaf(h1, w.y, a1.y);
            a1.z = fmaf(h1, w.z, a1.z); a1.w = fmaf(h1, w.w, a1.w);
            a2.x = fmaf(h2, w.x, a2.x); a2.y = fmaf(h2, w.y, a2.y);
            a2.z = fmaf(h2, w.z, a2.z); a2.w = fmaf(h2, w.w, a2.w);
            a3.x = fmaf(h3, w.x, a3.x); a3.y = fmaf(h3, w.y, a3.y);
            a3.z = fmaf(h3, w.z, a3.z); a3.w = fmaf(h3, w.w, a3.w);
        }
        float4 qcv = *(const float4*)&qc[jg * 4];
        float4 wv  = *(const float4*)&w23[jg * 4];
        float s0 = relu_dot(a0, qcv, wv);
        float s1 = relu_dot(a1, qcv, wv);
        float s2 = relu_dot(a2, qcv, wv);
        float s3 = relu_dot(a3, qcv, wv);
        #pragma unroll
        for (int off = 1; off < 16; off <<= 1) {
            s0 += __shfl_xor(s0, off, 16);
            s1 += __shfl_xor(s1, off, 16);
            s2 += __shfl_xor(s2, off, 16);
            s3 += __shfl_xor(s3, off, 16);
        }
        if (jg == 0) {
            float sv[4] = {s0, s1, s2, s3};
            #pragma unroll
            for (int i = 0; i < 4; ++i) {
                int l = l0 + i;
                if (l < NL) score[l] = (iml[l] == 0) ? 0.f : (c23s + sv[i]);
            }
        }
    }
    __syncthreads();

    // ---- phase 3: pooled + write feat = [ie | pooled | u] ----
    const size_t base = (size_t)bn * 128;
    if (t < 48) {
        float p = 0.f;
        #pragma unroll 5
        for (int l = 0; l < NL; ++l) p = fmaf(score[l], he[l][t], p);
        feat[base + 48 + t] = p;
    } else if (t < 96) {
        feat[base + (t - 48)] = q[t - 48];
    } else if (t < 128) {
        feat[base + t] = u[t - 96];
    }
}

__global__ __launch_bounds__(256) void k2_fc(
    const float* __restrict__ feat,   // [8192][128]
    const float* __restrict__ fw1, const float* __restrict__ fb1,   // [128][200],[200]
    const float* __restrict__ fw2, const float* __restrict__ fb2,   // [200][80],[80]
    const float* __restrict__ fw3, const float* __restrict__ fb3,   // [80],[1]
    const int* __restrict__ items,
    float* __restrict__ logits)       // [8192]
{
    const int blk = blockIdx.x;       // 256 blocks x 32 rows
    const int t = threadIdx.x;
    __shared__ float fl[32 * 128];
    __shared__ float x1[32][200];
    __shared__ float x2[32][80];

    const float4* src = (const float4*)(feat + (size_t)blk * 32 * 128);
    for (int e = t; e < 32 * 32; e += 256) ((float4*)fl)[e] = src[e];
    __syncthreads();

    if (t < 200) {
        float acc[32];
        #pragma unroll
        for (int r = 0; r < 32; ++r) acc[r] = fb1[t];
        for (int k = 0; k < 128; ++k) {
            float w = fw1[k * 200 + t];
            #pragma unroll
            for (int r = 0; r < 32; ++r) acc[r] = fmaf(fl[r * 128 + k], w, acc[r]);
        }
        #pragma unroll
        for (int r = 0; r < 32; ++r) x1[r][t] = fmaxf(acc[r], 0.f);
    }
    __syncthreads();

    if (t < 240) {
        const int j = t % 80, rg = t / 80;   // rg in 0..2, rows r = rg + 3*i
        float acc[11];
        #pragma unroll
        for (int i = 0; i < 11; ++i) acc[i] = fb2[j];
        for (int k = 0; k < 200; ++k) {
            float w = fw2[k * 80 + j];
            #pragma unroll
            for (int i = 0; i < 11; ++i) {
                int r = rg + 3 * i;
                if (r < 32) acc[i] = fmaf(x1[r][k], w, acc[i]);
            }
        }
        #pragma unroll
        for (int i = 0; i < 11; ++i) {
            int r = rg + 3 * i;
            if (r < 32) x2[r][j] = fmaxf(acc[i], 0.f);
        }
    }
    __syncthreads();

    if (t < 32) {
        float s = fb3[0];
        #pragma unroll 8
        for (int k = 0; k < 80; ++k) s = fmaf(x2[t][k], fw3[k], s);
        int bn = blk * 32 + t;
        float lg = (items[bn] == 0) ? -INFINITY : 1.f / (1.f + __expf(-s));
        logits[bn] = lg;
    }
}

__global__ __launch_bounds__(256) void k3_softmax(
    const float* __restrict__ logits, float* __restrict__ out)
{
    const int b = blockIdx.x, t = threadIdx.x;
    __shared__ float red[4];
    float v = logits[b * 256 + t];
    float m = v;
    #pragma unroll
    for (int off = 32; off; off >>= 1) m = fmaxf(m, __shfl_xor(m, off, 64));
    if ((t & 63) == 0) red[t >> 6] = m;
    __syncthreads();
    float mx = fmaxf(fmaxf(red[0], red[1]), fmaxf(red[2], red[3]));
    float e = __expf(v - mx);
    float s = e;
    #pragma unroll
    for (int off = 32; off; off >>= 1) s += __shfl_xor(s, off, 64);
    __syncthreads();
    if ((t & 63) == 0) red[t >> 6] = s;
    __syncthreads();
    float tot = red[0] + red[1] + red[2] + red[3];
    out[b * 256 + t] = e / tot;
}

extern "C" void kernel_launch(void* const* d_in, const int* in_sizes, int n_in,
                              void* d_out, int out_size, void* d_ws, size_t ws_size,
                              hipStream_t stream)
{
    const float* emb_user = (const float*)d_in[0];
    const float* emb_item = (const float*)d_in[1];
    const float* emb_cate = (const float*)d_in[2];
    const float* aw1 = (const float*)d_in[3];
    const float* ab1 = (const float*)d_in[4];
    const float* aw2 = (const float*)d_in[5];
    const float* ab2 = (const float*)d_in[6];
    const float* aw3 = (const float*)d_in[7];
    const float* ab3 = (const float*)d_in[8];
    const float* fw1 = (const float*)d_in[9];
    const float* fb1 = (const float*)d_in[10];
    const float* fw2 = (const float*)d_in[11];
    const float* fb2 = (const float*)d_in[12];
    const float* fw3 = (const float*)d_in[13];
    const float* fb3 = (const float*)d_in[14];
    const int* user  = (const int*)d_in[15];
    const int* items = (const int*)d_in[16];
    const int* cates = (const int*)d_in[17];
    const int* ii    = (const int*)d_in[18];
    const int* ic    = (const int*)d_in[19];

    float* feat   = (float*)d_ws;              // 8192*128 f32 = 4 MB
    float* logits = feat + (size_t)BN_TOT * 128;

    k1_attn<<<BN_TOT, 256, 0, stream>>>(emb_user, emb_item, emb_cate,
                                        aw1, ab1, aw2, ab2, aw3, ab3,
                                        user, items, cates, ii, ic, feat);
    k2_fc<<<BN_TOT / 32, 256, 0, stream>>>(feat, fw1, fb1, fw2, fb2, fw3, fb3,
                                           items, logits);
    k3_softmax<<<32, 256, 0, stream>>>(logits, (float*)d_out);
}

// Round 2
// 237.064 us; speedup vs baseline: 1.2607x; 1.2607x over previous
//
#include <hip/hip_runtime.h>
#include <math.h>

// DIN forward, MI355X gfx950. B=32,N=256,L=50, D=48 -> feat 128 -> 200 -> 80 -> 1.
// k1: per-(b,n) attention. Algebra: ai@W1 = [q@(W1a+W1c)+b1] + he@[W1b-W1c+diag(q)W1d]
//     layers 2+3 collapse: score = relu(h1) . (W2@w3) + (b2@w3+b3).
//     GEMM he[52x48]@Wq[48x64] done with mfma_f32_16x16x32_bf16 (M pad 64, K pad 64).
// k2: 128->200->80->1 MLP, 16 rows/block, 512 blocks.
// k3: masked softmax over N=256.

typedef short short8 __attribute__((ext_vector_type(8)));
typedef float f32x4 __attribute__((ext_vector_type(4)));

#define NL 50
#define BN_TOT 8192

__device__ __forceinline__ ushort f2bf(float x) {
    union { float f; uint u; } v; v.f = x;
    uint r = v.u + 0x7FFFu + ((v.u >> 16) & 1u);
    return (ushort)(r >> 16);
}
__device__ __forceinline__ float bf2f(ushort h) {
    union { uint u; float f; } v; v.u = ((uint)h) << 16;
    return v.f;
}

// LDS tiles heb/wqt: 64 rows x 64 bf16 (128 B/row). 16B chunks XOR-swizzled:
// byte = row*128 + ((chunk ^ (row&7))<<4) + within. ushort index = row*64 + ((chunk^(row&7))<<3) + w.

__global__ __launch_bounds__(256) void k1_attn(
    const float* __restrict__ emb_user,
    const float* __restrict__ emb_item,
    const float* __restrict__ emb_cate,
    const float* __restrict__ w1,   // [192][64]
    const float* __restrict__ b1,   // [64]
    const float* __restrict__ w2,   // [64][16]
    const float* __restrict__ b2,   // [16]
    const float* __restrict__ w3,   // [16]
    const float* __restrict__ b3,   // [1]
    const int* __restrict__ user,
    const int* __restrict__ items,
    const int* __restrict__ cates,
    const int* __restrict__ ii,
    const int* __restrict__ ic,
    ushort* __restrict__ feat)      // [8192][128] bf16
{
    const int bn = blockIdx.x;
    const int t  = threadIdx.x;

    __shared__ ushort heb[64 * 64];   // he bf16, swizzled. rows 50-63 uninit (discarded rows)
    __shared__ ushort wqt[64 * 64];   // Wq^T bf16, swizzled: row j (out col), col k. k>=48 zeroed.
    __shared__ float q[48];
    __shared__ float u[32];
    __shared__ float qc[64];
    __shared__ float w23[64];
    __shared__ float score[52];
    __shared__ int   iml[52];
    __shared__ float c23s;

    // ---- phase 0: gathers + pads ----
    if (t < 32)       q[t]      = emb_item[(size_t)items[bn] * 32 + t];
    else if (t < 48)  q[t]      = emb_cate[(size_t)cates[bn] * 16 + (t - 32)];
    else if (t < 80)  u[t - 48] = emb_user[(size_t)user[bn]  * 32 + (t - 48)];
    if (t >= 80 && t < 130) iml[t - 80] = ii[bn * NL + (t - 80)];

    if (t < 128) {   // zero Wq^T k-pad (k 48..63) for all 64 j rows
        int j = t >> 1, c = 6 + (t & 1);
        short8 z = {0,0,0,0,0,0,0,0};
        *(short8*)&wqt[j * 64 + ((c ^ (j & 7)) << 3)] = z;
    }

    // he gather: 50 rows x 6 data chunks (8 bf16 each) + 50 x 2 zero chunks
    for (int e = t; e < 400; e += 256) {
        union { short8 v; ushort s[8]; } o;
        int l, c;
        if (e < 300) {
            l = e / 6; c = e - l * 6;
            float4 f0, f1;
            if (c < 4) {
                const float* p = emb_item + (size_t)ii[bn * NL + l] * 32 + c * 8;
                f0 = *(const float4*)p; f1 = *(const float4*)(p + 4);
            } else {
                const float* p = emb_cate + (size_t)ic[bn * NL + l] * 16 + (c - 4) * 8;
                f0 = *(const float4*)p; f1 = *(const float4*)(p + 4);
            }
            o.s[0] = f2bf(f0.x); o.s[1] = f2bf(f0.y); o.s[2] = f2bf(f0.z); o.s[3] = f2bf(f0.w);
            o.s[4] = f2bf(f1.x); o.s[5] = f2bf(f1.y); o.s[6] = f2bf(f1.z); o.s[7] = f2bf(f1.w);
        } else {
            int r = e - 300; l = r >> 1; c = 6 + (r & 1);
            o.v = short8{0,0,0,0,0,0,0,0};
        }
        *(short8*)&heb[l * 64 + ((c ^ (l & 7)) << 3)] = o.v;
    }
    __syncthreads();

    // ---- phase 1: WqT (bf16), qc, w23, c23 ----
    for (int e = t; e < 3072; e += 256) {
        int k = e >> 6, j = e & 63;
        float wv = w1[(48 + k) * 64 + j] - w1[(96 + k) * 64 + j]
                 + q[k] * w1[(144 + k) * 64 + j];
        wqt[j * 64 + (((k >> 3) ^ (j & 7)) << 3) + (k & 7)] = f2bf(wv);
    }
    if (t < 64) {
        float a = b1[t];
        #pragma unroll 4
        for (int k = 0; k < 48; ++k)
            a = fmaf(q[k], w1[k * 64 + t] + w1[(96 + k) * 64 + t], a);
        qc[t] = a;
        float s = 0.f;
        #pragma unroll
        for (int jj = 0; jj < 16; ++jj) s = fmaf(w2[t * 16 + jj], w3[jj], s);
        w23[t] = s;
    }
    if (t == 192) {
        float c = b3[0];
        #pragma unroll
        for (int jj = 0; jj < 16; ++jj) c = fmaf(b2[jj], w3[jj], c);
        c23s = c;
    }
    __syncthreads();

    // ---- phase 2: S = he @ Wq via MFMA; score = relu(S+qc).w23 + c23 ----
    {
        const int w = t >> 6, l = t & 63;
        const int col = l & 15, g = l >> 4;
        f32x4 acc0 = {0,0,0,0}, acc1 = acc0, acc2 = acc0, acc3 = acc0;
        const int ar = w * 16 + col;            // A row (D row base)
        #pragma unroll
        for (int ks = 0; ks < 2; ++ks) {
            int ch = ks * 4 + g;
            short8 a  = *(short8*)&heb[ar * 64 + ((ch ^ (ar & 7)) << 3)];
            int bo = (ch ^ (col & 7)) << 3;
            short8 b0 = *(short8*)&wqt[(col)      * 64 + bo];
            short8 b1 = *(short8*)&wqt[(16 + col) * 64 + bo];
            short8 b2 = *(short8*)&wqt[(32 + col) * 64 + bo];
            short8 b3 = *(short8*)&wqt[(48 + col) * 64 + bo];
            acc0 = __builtin_amdgcn_mfma_f32_16x16x32_bf16(a, b0, acc0, 0, 0, 0);
            acc1 = __builtin_amdgcn_mfma_f32_16x16x32_bf16(a, b1, acc1, 0, 0, 0);
            acc2 = __builtin_amdgcn_mfma_f32_16x16x32_bf16(a, b2, acc2, 0, 0, 0);
            acc3 = __builtin_amdgcn_mfma_f32_16x16x32_bf16(a, b3, acc3, 0, 0, 0);
        }
        float qc0 = qc[col],      qc1 = qc[16 + col], qc2 = qc[32 + col], qc3 = qc[48 + col];
        float wv0 = w23[col],     wv1 = w23[16 + col], wv2 = w23[32 + col], wv3 = w23[48 + col];
        float c23 = c23s;
        #pragma unroll
        for (int i = 0; i < 4; ++i) {
            float s = fmaxf(acc0[i] + qc0, 0.f) * wv0
                    + fmaxf(acc1[i] + qc1, 0.f) * wv1
                    + fmaxf(acc2[i] + qc2, 0.f) * wv2
                    + fmaxf(acc3[i] + qc3, 0.f) * wv3;
            s += __shfl_xor(s, 1, 16);
            s += __shfl_xor(s, 2, 16);
            s += __shfl_xor(s, 4, 16);
            s += __shfl_xor(s, 8, 16);
            if (col == 0) {
                int row = w * 16 + g * 4 + i;   // D layout: row=(lane>>4)*4+reg
                if (row < NL) score[row] = (iml[row] == 0) ? 0.f : (c23 + s);
            }
        }
    }
    __syncthreads();

    // ---- phase 3: pooled + write feat = [ie | pooled | u] (bf16) ----
    const size_t fb = (size_t)bn * 128;
    if (t < 48) {
        float p = 0.f;
        const int ch = t >> 3, wi = t & 7;
        #pragma unroll 5
        for (int l = 0; l < NL; ++l) {
            ushort h = heb[l * 64 + ((ch ^ (l & 7)) << 3) + wi];
            p = fmaf(score[l], bf2f(h), p);
        }
        feat[fb + 48 + t] = f2bf(p);
    } else if (t < 96) {
        feat[fb + (t - 48)] = f2bf(q[t - 48]);
    } else if (t < 128) {
        feat[fb + t] = f2bf(u[t - 96]);
    }
}

__global__ __launch_bounds__(512) void k2_fc(
    const ushort* __restrict__ feat,  // [8192][128] bf16
    const float* __restrict__ fw1, const float* __restrict__ fb1,   // [128][200],[200]
    const float* __restrict__ fw2, const float* __restrict__ fb2,   // [200][80],[80]
    const float* __restrict__ fw3, const float* __restrict__ fb3,   // [80],[1]
    const int* __restrict__ items,
    float* __restrict__ logits)       // [8192]
{
    const int blk = blockIdx.x;       // 512 blocks x 16 rows
    const int t = threadIdx.x;
    __shared__ float xs[16 * 128];
    __shared__ float x1[16 * 200];
    __shared__ float x2[16 * 80];

    // stage 16x128 bf16 -> f32
    {
        const ushort4* src = (const ushort4*)(feat + (size_t)blk * 16 * 128);
        ushort4 v = src[t];
        float4 o = { bf2f(v.x), bf2f(v.y), bf2f(v.z), bf2f(v.w) };
        ((float4*)xs)[t] = o;
    }
    __syncthreads();

    if (t < 400) {
        const int h = (t >= 200) ? 1 : 0;
        const int j = t - h * 200;
        const float* xrow = xs + h * 8 * 128;
        float bias = fb1[j];
        float acc[8];
        #pragma unroll
        for (int r = 0; r < 8; ++r) acc[r] = bias;
        #pragma unroll 2
        for (int k = 0; k < 128; ++k) {
            float wv = fw1[k * 200 + j];
            #pragma unroll
            for (int r = 0; r < 8; ++r) acc[r] = fmaf(xrow[r * 128 + k], wv, acc[r]);
        }
        #pragma unroll
        for (int r = 0; r < 8; ++r) x1[(h * 8 + r) * 200 + j] = fmaxf(acc[r], 0.f);
    }
    __syncthreads();

    if (t < 480) {
        const int g = t / 80;
        const int j = t - g * 80;
        float bias = fb2[j];
        float acc[3];
        #pragma unroll
        for (int i = 0; i < 3; ++i) acc[i] = bias;
        #pragma unroll 2
        for (int k = 0; k < 200; ++k) {
            float wv = fw2[k * 80 + j];
            #pragma unroll
            for (int i = 0; i < 3; ++i) {
                int r = g + 6 * i;
                if (r < 16) acc[i] = fmaf(x1[r * 200 + k], wv, acc[i]);
            }
        }
        #pragma unroll
        for (int i = 0; i < 3; ++i) {
            int r = g + 6 * i;
            if (r < 16) x2[r * 80 + j] = fmaxf(acc[i], 0.f);
        }
    }
    __syncthreads();

    if (t < 16) {
        float s = fb3[0];
        #pragma unroll 8
        for (int k = 0; k < 80; ++k) s = fmaf(x2[t * 80 + k], fw3[k], s);
        int bn = blk * 16 + t;
        float lg = (items[bn] == 0) ? -INFINITY : 1.f / (1.f + __expf(-s));
        logits[bn] = lg;
    }
}

__global__ __launch_bounds__(256) void k3_softmax(
    const float* __restrict__ logits, float* __restrict__ out)
{
    const int b = blockIdx.x, t = threadIdx.x;
    __shared__ float red[4];
    float v = logits[b * 256 + t];
    float m = v;
    #pragma unroll
    for (int off = 32; off; off >>= 1) m = fmaxf(m, __shfl_xor(m, off, 64));
    if ((t & 63) == 0) red[t >> 6] = m;
    __syncthreads();
    float mx = fmaxf(fmaxf(red[0], red[1]), fmaxf(red[2], red[3]));
    float e = __expf(v - mx);
    float s = e;
    #pragma unroll
    for (int off = 32; off; off >>= 1) s += __shfl_xor(s, off, 64);
    __syncthreads();
    if ((t & 63) == 0) red[t >> 6] = s;
    __syncthreads();
    float tot = red[0] + red[1] + red[2] + red[3];
    out[b * 256 + t] = e / tot;
}

extern "C" void kernel_launch(void* const* d_in, const int* in_sizes, int n_in,
                              void* d_out, int out_size, void* d_ws, size_t ws_size,
                              hipStream_t stream)
{
    const float* emb_user = (const float*)d_in[0];
    const float* emb_item = (const float*)d_in[1];
    const float* emb_cate = (const float*)d_in[2];
    const float* aw1 = (const float*)d_in[3];
    const float* ab1 = (const float*)d_in[4];
    const float* aw2 = (const float*)d_in[5];
    const float* ab2 = (const float*)d_in[6];
    const float* aw3 = (const float*)d_in[7];
    const float* ab3 = (const float*)d_in[8];
    const float* fw1 = (const float*)d_in[9];
    const float* fb1 = (const float*)d_in[10];
    const float* fw2 = (const float*)d_in[11];
    const float* fb2 = (const float*)d_in[12];
    const float* fw3 = (const float*)d_in[13];
    const float* fb3 = (const float*)d_in[14];
    const int* user  = (const int*)d_in[15];
    const int* items = (const int*)d_in[16];
    const int* cates = (const int*)d_in[17];
    const int* ii    = (const int*)d_in[18];
    const int* ic    = (const int*)d_in[19];

    ushort* feat  = (ushort*)d_ws;                              // 8192*128 bf16 = 2 MB
    float* logits = (float*)((char*)d_ws + (size_t)BN_TOT * 128 * sizeof(ushort));

    k1_attn<<<BN_TOT, 256, 0, stream>>>(emb_user, emb_item, emb_cate,
                                        aw1, ab1, aw2, ab2, aw3, ab3,
                                        user, items, cates, ii, ic, feat);
    k2_fc<<<BN_TOT / 16, 512, 0, stream>>>(feat, fw1, fb1, fw2, fb2, fw3, fb3,
                                           items, logits);
    k3_softmax<<<32, 256, 0, stream>>>(logits, (float*)d_out);
}

// Round 3
// 152.073 us; speedup vs baseline: 1.9653x; 1.5589x over previous
//
#include <hip/hip_runtime.h>
#include <math.h>

// DIN forward, MI355X gfx950. B=32,N=256,L=50, D=48; feat 128 -> 200 -> 80 -> 1.
// Algebra: ai@W1 = qc + [he | he*q] @ Wcat   (Wcat constant across bn!)
//   Wcat[0:48]  = W1b - W1c ; Wcat[48:96] = W1d ; qc = q@(W1a+W1c)+b1
//   layers 2+3 of LAU collapse: score = relu(h1) . (W2@w3) + (b2@w3+b3)
// k0: pre-lay ALL weights as bf16 MFMA B-fragments in ws.
// kA: per-bn gather + 48 MFMA (A=[he|he*q]) + score + pooled -> feat bf16.
// k2: feat@fw1 relu @fw2 relu .fw3 -> sigmoid logits, pure MFMA (94/wave).
// k3: masked softmax over N=256.

typedef short short8 __attribute__((ext_vector_type(8)));
typedef float f32x4 __attribute__((ext_vector_type(4)));

#define NL 50
#define BN_TOT 8192

__device__ __forceinline__ ushort f2bf(float x) {
    union { float f; uint u; } v; v.f = x;
    uint r = v.u + 0x7FFFu + ((v.u >> 16) & 1u);
    return (ushort)(r >> 16);
}
__device__ __forceinline__ float bf2f(ushort h) {
    union { uint u; float f; } v; v.u = ((uint)h) << 16;
    return v.f;
}

// ---- ws layout (bytes) ----
#define WS_FEAT   0                       // bf16 8192*128  = 2097152
#define WS_LOGITS 2097152                 // f32  8192      = 32768
#define WS_W1FRAG 2129920                 // bf16 52*512    = 53248
#define WS_W2FRAG 2183168                 // bf16 42*512    = 43008
#define WS_WCFRAG 2226176                 // bf16 12*512    = 12288
#define WS_W1AC   2238464                 // f32  48*64     = 12288
#define WS_W23    2250752                 // f32  64        = 256
#define WS_C23    2251008                 // f32  1

// ================= k0: weight prep =================
__global__ __launch_bounds__(256) void k0_prep(
    const float* __restrict__ aw1, const float* __restrict__ ab2,
    const float* __restrict__ aw2, const float* __restrict__ aw3,
    const float* __restrict__ ab3,
    const float* __restrict__ fw1, const float* __restrict__ fw2,
    ushort* __restrict__ W1frag, ushort* __restrict__ W2frag,
    ushort* __restrict__ WcFrag, float* __restrict__ W1ac,
    float* __restrict__ w23, float* __restrict__ c23)
{
    const int b = blockIdx.x, t = threadIdx.x;
    if (b < 104) {                       // W1frag: fw1[128][200] -> 13nt x 4ks
        int e = b * 256 + t;
        if (e < 26624) {
            int f = e >> 9, r = e & 511, l = r >> 3, j = r & 7;
            int nt = f >> 2, ks = f & 3;
            int k = ks * 32 + (l >> 4) * 8 + j, n = nt * 16 + (l & 15);
            float v = (n < 200) ? fw1[k * 200 + n] : 0.f;
            W1frag[e] = f2bf(v);
        }
    } else if (b < 188) {                // W2frag: fw2[200][80] -> 6nt x 7ks (pad K224,N96)
        int e = (b - 104) * 256 + t;
        if (e < 21504) {
            int f = e >> 9, r = e & 511, l = r >> 3, j = r & 7;
            int nt = f / 7, ks = f % 7;
            int k = ks * 32 + (l >> 4) * 8 + j, n = nt * 16 + (l & 15);
            float v = (k < 200 && n < 80) ? fw2[k * 80 + n] : 0.f;
            W2frag[e] = f2bf(v);
        }
    } else if (b < 212) {                // WcFrag: Wcat[96][64] -> 4nt x 3ks
        int e = (b - 188) * 256 + t;     // 6144 elems
        int f = e >> 9, r = e & 511, l = r >> 3, j = r & 7;
        int nt = f / 3, ks = f % 3;
        int k = ks * 32 + (l >> 4) * 8 + j, n = nt * 16 + (l & 15);
        float v = (k < 48) ? (aw1[(48 + k) * 64 + n] - aw1[(96 + k) * 64 + n])
                           : aw1[(144 + (k - 48)) * 64 + n];
        WcFrag[e] = f2bf(v);
    } else if (b < 224) {                // W1ac = W1a + W1c  f32 [48][64]
        int e = (b - 212) * 256 + t;
        if (e < 3072) {
            int k = e >> 6, j = e & 63;
            W1ac[e] = aw1[k * 64 + j] + aw1[(96 + k) * 64 + j];
        }
    } else {                             // w23, c23
        if (t < 64) {
            float s = 0.f;
            #pragma unroll
            for (int jj = 0; jj < 16; ++jj) s = fmaf(aw2[t * 16 + jj], aw3[jj], s);
            w23[t] = s;
        }
        if (t == 64) {
            float c = ab3[0];
            #pragma unroll
            for (int jj = 0; jj < 16; ++jj) c = fmaf(ab2[jj], aw3[jj], c);
            c23[0] = c;
        }
    }
}

// ================= kA: attention (1 wave = 1 bn) =================
__device__ __forceinline__ short8 lds8(const ushort* hb, int row, int c) {
    return *(const short8*)&hb[row * 56 + c * 8];
}
__device__ __forceinline__ short8 scale8(const ushort* hb, const float* qv,
                                         int row, int c, int qb) {
    short8 a = lds8(hb, row, c);
    union { short8 v; ushort s[8]; } o;
    const ushort* as = (const ushort*)&a;
    #pragma unroll
    for (int j = 0; j < 8; ++j) o.s[j] = f2bf(bf2f(as[j]) * qv[qb + j]);
    return o.v;
}

__global__ __launch_bounds__(256) void kA_attn(
    const float* __restrict__ emb_user,
    const float* __restrict__ emb_item,
    const float* __restrict__ emb_cate,
    const float* __restrict__ ab1,
    const int* __restrict__ user,
    const int* __restrict__ items,
    const int* __restrict__ cates,
    const int* __restrict__ ii,
    const int* __restrict__ ic,
    const ushort* __restrict__ WcFrag,
    const float* __restrict__ W1ac,
    const float* __restrict__ w23g,
    const float* __restrict__ c23g,
    ushort* __restrict__ feat)
{
    __shared__ __align__(16) ushort heb[4][64 * 56];   // he bf16 [64 rows][48+8pad]
    __shared__ __align__(16) float  q_lds[4][48];
    __shared__ __align__(16) float  u_lds[4][32];
    __shared__ float  qc_lds[4][64];
    __shared__ float  sc_lds[4][52];
    __shared__ int    imll[4][52];
    __shared__ int    icll[4][52];

    const int t = threadIdx.x;
    const int w = t >> 6, l = t & 63;
    const int bn = blockIdx.x * 4 + w;
    const int col = l & 15, g = l >> 4;

    const int it = items[bn], ct = cates[bn], ur = user[bn];
    ushort* hb = &heb[w][0];
    float* qv = &q_lds[w][0];

    // ---- P0: q, u, index gathers ----
    if (l < 12) {
        float4 v = (l < 8) ? ((const float4*)emb_item)[(size_t)it * 8 + l]
                           : ((const float4*)emb_cate)[(size_t)ct * 4 + (l - 8)];
        *(float4*)&q_lds[w][l * 4] = v;
    } else if (l >= 16 && l < 24) {
        *(float4*)&u_lds[w][(l - 16) * 4] = ((const float4*)emb_user)[(size_t)ur * 8 + (l - 16)];
    }
    if (l < NL) {
        imll[w][l] = ii[(size_t)bn * NL + l];
        icll[w][l] = ic[(size_t)bn * NL + l];
    }
    __syncthreads();

    // ---- P1: he gather -> LDS bf16 (rows >= 50 zeroed) ----
    #pragma unroll
    for (int e0 = 0; e0 < 384; e0 += 64) {
        int e = e0 + l;
        int row = e / 6, c = e - row * 6;
        union { short8 v; ushort s[8]; } o;
        o.v = short8{0,0,0,0,0,0,0,0};
        if (row < NL) {
            int k0 = c * 8;
            const float* src = (k0 < 32)
                ? emb_item + (size_t)imll[w][row] * 32 + k0
                : emb_cate + (size_t)icll[w][row] * 16 + (k0 - 32);
            float4 f0 = *(const float4*)src;
            float4 f1 = *(const float4*)(src + 4);
            o.s[0] = f2bf(f0.x); o.s[1] = f2bf(f0.y); o.s[2] = f2bf(f0.z); o.s[3] = f2bf(f0.w);
            o.s[4] = f2bf(f1.x); o.s[5] = f2bf(f1.y); o.s[6] = f2bf(f1.z); o.s[7] = f2bf(f1.w);
        }
        *(short8*)&hb[row * 56 + c * 8] = o.v;
    }

    // ---- P2: qc[j] = b1[j] + sum_k q[k] * W1ac[k][j]  (lane j) ----
    {
        float a = ab1[l];
        #pragma unroll 8
        for (int k = 0; k < 48; ++k)
            a = fmaf(qv[k], W1ac[k * 64 + l], a);
        qc_lds[w][l] = a;
    }
    __syncthreads();

    // ---- P3: S = [he | he*q] @ Wcat via MFMA ----
    f32x4 acc[4][4];
    #pragma unroll
    for (int m = 0; m < 4; ++m)
        #pragma unroll
        for (int n = 0; n < 4; ++n) acc[m][n] = f32x4{0,0,0,0};

    #pragma unroll
    for (int ks = 0; ks < 3; ++ks) {
        short8 af[4];
        #pragma unroll
        for (int mt = 0; mt < 4; ++mt) {
            int row = mt * 16 + col;
            if (ks == 0)       af[mt] = lds8(hb, row, g);
            else if (ks == 1)  af[mt] = (g < 2) ? lds8(hb, row, 4 + g)
                                                : scale8(hb, qv, row, g - 2, (g - 2) * 8);
            else               af[mt] = scale8(hb, qv, row, 2 + g, 16 + g * 8);
        }
        #pragma unroll
        for (int nt = 0; nt < 4; ++nt) {
            short8 bf = *(const short8*)&WcFrag[((nt * 3 + ks) * 64 + l) * 8];
            #pragma unroll
            for (int mt = 0; mt < 4; ++mt)
                acc[mt][nt] = __builtin_amdgcn_mfma_f32_16x16x32_bf16(af[mt], bf, acc[mt][nt], 0, 0, 0);
        }
    }

    // ---- P4: score = relu(S + qc) . w23 + c23, mask ----
    {
        float qcv[4], wv[4];
        #pragma unroll
        for (int nt = 0; nt < 4; ++nt) {
            qcv[nt] = qc_lds[w][nt * 16 + col];
            wv[nt]  = w23g[nt * 16 + col];
        }
        float c23 = c23g[0];
        #pragma unroll
        for (int mt = 0; mt < 4; ++mt) {
            #pragma unroll
            for (int i = 0; i < 4; ++i) {
                float s = fmaxf(acc[mt][0][i] + qcv[0], 0.f) * wv[0]
                        + fmaxf(acc[mt][1][i] + qcv[1], 0.f) * wv[1]
                        + fmaxf(acc[mt][2][i] + qcv[2], 0.f) * wv[2]
                        + fmaxf(acc[mt][3][i] + qcv[3], 0.f) * wv[3];
                s += __shfl_xor(s, 1, 16);
                s += __shfl_xor(s, 2, 16);
                s += __shfl_xor(s, 4, 16);
                s += __shfl_xor(s, 8, 16);
                int row = mt * 16 + g * 4 + i;
                if (col == 0 && row < NL)
                    sc_lds[w][row] = (imll[w][row] == 0) ? 0.f : (s + c23);
            }
        }
    }
    __syncthreads();

    // ---- P5: pooled + feat writes ----
    const size_t fb = (size_t)bn * 128;
    if (l < 48) {
        float p = 0.f;
        #pragma unroll 5
        for (int row = 0; row < NL; ++row)
            p = fmaf(sc_lds[w][row], bf2f(hb[row * 56 + l]), p);
        feat[fb + 48 + l] = f2bf(p);
        feat[fb + l] = f2bf(qv[l]);
    }
    if (l < 32) feat[fb + 96 + l] = f2bf(u_lds[w][l]);
}

// ================= k2: MLP 128->200->80->1, pure MFMA =================
__global__ __launch_bounds__(128) void k2_fc(
    const ushort* __restrict__ feat,
    const ushort* __restrict__ W1frag,
    const ushort* __restrict__ W2frag,
    const float* __restrict__ fb1, const float* __restrict__ fb2,
    const float* __restrict__ fw3, const float* __restrict__ fb3,
    const int* __restrict__ items,
    float* __restrict__ logits)
{
    __shared__ __align__(16) ushort x1s[2][16 * 256];  // [wave][16 rows][224+pad] swizzled

    const int t = threadIdx.x;
    const int wv = t >> 6, l = t & 63;
    const int r0 = blockIdx.x * 32 + wv * 16;
    const int col = l & 15, g = l >> 4;

    // ---- layer 1: 13nt x 4ks MFMA, A from feat global ----
    short8 afr[4];
    #pragma unroll
    for (int ks = 0; ks < 4; ++ks)
        afr[ks] = *(const short8*)&feat[(size_t)(r0 + col) * 128 + ks * 32 + g * 8];

    f32x4 acc[13];
    #pragma unroll
    for (int nt = 0; nt < 13; ++nt) acc[nt] = f32x4{0,0,0,0};
    #pragma unroll
    for (int nt = 0; nt < 13; ++nt)
        #pragma unroll
        for (int ks = 0; ks < 4; ++ks) {
            short8 bf = *(const short8*)&W1frag[((nt * 4 + ks) * 64 + l) * 8];
            acc[nt] = __builtin_amdgcn_mfma_f32_16x16x32_bf16(afr[ks], bf, acc[nt], 0, 0, 0);
        }

    // zero pad chunks 26,27 (k 208..223) of x1
    if (l < 32) {
        int row = l >> 1, c = 26 + (l & 1);
        *(short8*)&x1s[wv][row * 256 + ((c ^ (row & 7)) << 3)] = short8{0,0,0,0,0,0,0,0};
    }
    // relu + bias -> x1 LDS (bf16, XOR-swizzled chunks)
    #pragma unroll
    for (int nt = 0; nt < 13; ++nt) {
        int n = nt * 16 + col;
        float bias = (n < 200) ? fb1[n] : 0.f;
        #pragma unroll
        for (int i = 0; i < 4; ++i) {
            int row = g * 4 + i;
            float v = fmaxf(acc[nt][i] + bias, 0.f);
            int sw = (n >> 3) ^ (row & 7);
            x1s[wv][row * 256 + sw * 8 + (n & 7)] = f2bf(v);
        }
    }
    __syncthreads();

    // ---- layer 2: 6nt x 7ks MFMA, A from x1s ----
    f32x4 acc2[6];
    #pragma unroll
    for (int nt = 0; nt < 6; ++nt) acc2[nt] = f32x4{0,0,0,0};
    #pragma unroll
    for (int ks = 0; ks < 7; ++ks) {
        int chunk = ks * 4 + g;
        short8 a = *(const short8*)&x1s[wv][col * 256 + ((chunk ^ (col & 7)) << 3)];
        #pragma unroll
        for (int nt = 0; nt < 6; ++nt) {
            short8 bf = *(const short8*)&W2frag[((nt * 7 + ks) * 64 + l) * 8];
            acc2[nt] = __builtin_amdgcn_mfma_f32_16x16x32_bf16(a, bf, acc2[nt], 0, 0, 0);
        }
    }

    // ---- layer 3: dot over 80 + sigmoid + mask ----
    {
        float s[4] = {0.f, 0.f, 0.f, 0.f};
        #pragma unroll
        for (int nt = 0; nt < 5; ++nt) {
            int n = nt * 16 + col;
            float b2v = fb2[n], w3v = fw3[n];
            #pragma unroll
            for (int i = 0; i < 4; ++i)
                s[i] = fmaf(fmaxf(acc2[nt][i] + b2v, 0.f), w3v, s[i]);
        }
        #pragma unroll
        for (int i = 0; i < 4; ++i) {
            s[i] += __shfl_xor(s[i], 1, 16);
            s[i] += __shfl_xor(s[i], 2, 16);
            s[i] += __shfl_xor(s[i], 4, 16);
            s[i] += __shfl_xor(s[i], 8, 16);
        }
        if (col == 0) {
            float b3 = fb3[0];
            #pragma unroll
            for (int i = 0; i < 4; ++i) {
                int row = r0 + g * 4 + i;
                float lg = (items[row] == 0) ? -INFINITY
                                             : 1.f / (1.f + __expf(-(s[i] + b3)));
                logits[row] = lg;
            }
        }
    }
}

// ================= k3: masked softmax =================
__global__ __launch_bounds__(256) void k3_softmax(
    const float* __restrict__ logits, float* __restrict__ out)
{
    const int b = blockIdx.x, t = threadIdx.x;
    __shared__ float red[4];
    float v = logits[b * 256 + t];
    float m = v;
    #pragma unroll
    for (int off = 32; off; off >>= 1) m = fmaxf(m, __shfl_xor(m, off, 64));
    if ((t & 63) == 0) red[t >> 6] = m;
    __syncthreads();
    float mx = fmaxf(fmaxf(red[0], red[1]), fmaxf(red[2], red[3]));
    float e = __expf(v - mx);
    float s = e;
    #pragma unroll
    for (int off = 32; off; off >>= 1) s += __shfl_xor(s, off, 64);
    __syncthreads();
    if ((t & 63) == 0) red[t >> 6] = s;
    __syncthreads();
    float tot = red[0] + red[1] + red[2] + red[3];
    out[b * 256 + t] = e / tot;
}

extern "C" void kernel_launch(void* const* d_in, const int* in_sizes, int n_in,
                              void* d_out, int out_size, void* d_ws, size_t ws_size,
                              hipStream_t stream)
{
    const float* emb_user = (const float*)d_in[0];
    const float* emb_item = (const float*)d_in[1];
    const float* emb_cate = (const float*)d_in[2];
    const float* aw1 = (const float*)d_in[3];
    const float* ab1 = (const float*)d_in[4];
    const float* aw2 = (const float*)d_in[5];
    const float* ab2 = (const float*)d_in[6];
    const float* aw3 = (const float*)d_in[7];
    const float* ab3 = (const float*)d_in[8];
    const float* fw1 = (const float*)d_in[9];
    const float* fb1 = (const float*)d_in[10];
    const float* fw2 = (const float*)d_in[11];
    const float* fb2 = (const float*)d_in[12];
    const float* fw3 = (const float*)d_in[13];
    const float* fb3 = (const float*)d_in[14];
    const int* user  = (const int*)d_in[15];
    const int* items = (const int*)d_in[16];
    const int* cates = (const int*)d_in[17];
    const int* ii    = (const int*)d_in[18];
    const int* ic    = (const int*)d_in[19];

    char* ws = (char*)d_ws;
    ushort* feat   = (ushort*)(ws + WS_FEAT);
    float*  logits = (float*) (ws + WS_LOGITS);
    ushort* W1frag = (ushort*)(ws + WS_W1FRAG);
    ushort* W2frag = (ushort*)(ws + WS_W2FRAG);
    ushort* WcFrag = (ushort*)(ws + WS_WCFRAG);
    float*  W1ac   = (float*) (ws + WS_W1AC);
    float*  w23    = (float*) (ws + WS_W23);
    float*  c23    = (float*) (ws + WS_C23);

    k0_prep<<<225, 256, 0, stream>>>(aw1, ab2, aw2, aw3, ab3, fw1, fw2,
                                     W1frag, W2frag, WcFrag, W1ac, w23, c23);
    kA_attn<<<BN_TOT / 4, 256, 0, stream>>>(emb_user, emb_item, emb_cate, ab1,
                                            user, items, cates, ii, ic,
                                            WcFrag, W1ac, w23, c23, feat);
    k2_fc<<<BN_TOT / 32, 128, 0, stream>>>(feat, W1frag, W2frag,
                                           fb1, fb2, fw3, fb3, items, logits);
    k3_softmax<<<32, 256, 0, stream>>>(logits, (float*)d_out);
}

// Round 4
// 142.118 us; speedup vs baseline: 2.1029x; 1.0701x over previous
//
#include <hip/hip_runtime.h>
#include <hip/hip_bf16.h>
#include <math.h>

// DIN forward, MI355X gfx950. B=32,N=256,L=50, D=48; feat 128 -> 200 -> 80 -> 1.
// Algebra: ai@W1 = qc + [he | he*q] @ Wcat   (Wcat constant across bn)
//   qc = q@(W1a+W1c) + b1, computed via MFMA with a folded bias row (k=48 -> 1*b1)
//   layers 2+3 of LAU collapse: score = relu(h1) . (W2@w3) + (b2@w3+b3)
// k0: pre-lay ALL weights as bf16 MFMA B-fragments in ws.
// kA: per-bn attention, fully wave-private (NO __syncthreads).
// k2: MLP via MFMA, 1 wave = 16 rows, wave-private LDS (NO __syncthreads).
// k3: masked softmax over N=256.

typedef short short8 __attribute__((ext_vector_type(8)));
typedef float f32x4 __attribute__((ext_vector_type(4)));

#define NL 50
#define BN_TOT 8192

__device__ __forceinline__ ushort f2bf(float x) {
    union { __hip_bfloat16 b; ushort u; } c;
    c.b = __float2bfloat16(x);          // RNE; compiler packs pairs into v_cvt_pk_bf16_f32
    return c.u;
}
__device__ __forceinline__ float bf2f(ushort h) {
    union { uint u; float f; } v; v.u = ((uint)h) << 16;
    return v.f;
}
// same-wave LDS RAW boundary: DS ops complete in order per wave; fence compiler + counters
__device__ __forceinline__ void wave_lds_fence() {
    asm volatile("s_waitcnt lgkmcnt(0)" ::: "memory");
}

// ---- ws layout (bytes) ----
#define WS_FEAT   0                       // bf16 8192*128  = 2097152
#define WS_LOGITS 2097152                 // f32  8192      = 32768
#define WS_W1FRAG 2129920                 // bf16 52*512    = 53248
#define WS_W2FRAG 2183168                 // bf16 42*512    = 43008
#define WS_WCFRAG 2226176                 // bf16 12*512    = 12288
#define WS_WACF   2238464                 // bf16 8*512     = 8192
#define WS_W23    2250752                 // f32  64        = 256
#define WS_C23    2251008                 // f32  1

// ================= k0: weight prep =================
__global__ __launch_bounds__(256) void k0_prep(
    const float* __restrict__ aw1, const float* __restrict__ ab1,
    const float* __restrict__ ab2,
    const float* __restrict__ aw2, const float* __restrict__ aw3,
    const float* __restrict__ ab3,
    const float* __restrict__ fw1, const float* __restrict__ fw2,
    ushort* __restrict__ W1frag, ushort* __restrict__ W2frag,
    ushort* __restrict__ WcFrag, ushort* __restrict__ WacF,
    float* __restrict__ w23, float* __restrict__ c23)
{
    const int b = blockIdx.x, t = threadIdx.x;
    if (b < 104) {                       // W1frag: fw1[128][200] -> 13nt x 4ks
        int e = b * 256 + t;
        if (e < 26624) {
            int f = e >> 9, r = e & 511, l = r >> 3, j = r & 7;
            int nt = f >> 2, ks = f & 3;
            int k = ks * 32 + (l >> 4) * 8 + j, n = nt * 16 + (l & 15);
            float v = (n < 200) ? fw1[k * 200 + n] : 0.f;
            W1frag[e] = f2bf(v);
        }
    } else if (b < 188) {                // W2frag: fw2[200][80] -> 6nt x 7ks (pad K224,N96)
        int e = (b - 104) * 256 + t;
        if (e < 21504) {
            int f = e >> 9, r = e & 511, l = r >> 3, j = r & 7;
            int nt = f / 7, ks = f % 7;
            int k = ks * 32 + (l >> 4) * 8 + j, n = nt * 16 + (l & 15);
            float v = (k < 200 && n < 80) ? fw2[k * 80 + n] : 0.f;
            W2frag[e] = f2bf(v);
        }
    } else if (b < 212) {                // WcFrag: Wcat[96][64] -> 4nt x 3ks
        int e = (b - 188) * 256 + t;     // 6144 elems
        int f = e >> 9, r = e & 511, l = r >> 3, j = r & 7;
        int nt = f / 3, ks = f % 3;
        int k = ks * 32 + (l >> 4) * 8 + j, n = nt * 16 + (l & 15);
        float v = (k < 48) ? (aw1[(48 + k) * 64 + n] - aw1[(96 + k) * 64 + n])
                           : aw1[(144 + (k - 48)) * 64 + n];
        WcFrag[e] = f2bf(v);
    } else if (b < 228) {                // WacF: (W1a+W1c)[48][64] + bias row k=48 -> 4nt x 2ks
        int e = (b - 212) * 256 + t;     // 4096 elems
        int f = e >> 9, r = e & 511, l = r >> 3, j = r & 7;
        int nt = f >> 1, ks = f & 1;
        int k = ks * 32 + (l >> 4) * 8 + j, n = nt * 16 + (l & 15);
        float v = (k < 48) ? (aw1[k * 64 + n] + aw1[(96 + k) * 64 + n])
                           : ((k == 48) ? ab1[n] : 0.f);
        WacF[e] = f2bf(v);
    } else {                             // w23, c23
        if (t < 64) {
            float s = 0.f;
            #pragma unroll
            for (int jj = 0; jj < 16; ++jj) s = fmaf(aw2[t * 16 + jj], aw3[jj], s);
            w23[t] = s;
        }
        if (t == 64) {
            float c = ab3[0];
            #pragma unroll
            for (int jj = 0; jj < 16; ++jj) c = fmaf(ab2[jj], aw3[jj], c);
            c23[0] = c;
        }
    }
}

// ================= kA: attention (1 wave = 1 bn, no barriers) =================
__device__ __forceinline__ short8 lds8(const ushort* hb, int row, int c) {
    return *(const short8*)&hb[row * 56 + c * 8];
}
__device__ __forceinline__ short8 scale8(const ushort* hb, const float* qv,
                                         int row, int c, int qb) {
    short8 a = lds8(hb, row, c);
    union { short8 v; ushort s[8]; } o;
    const ushort* as = (const ushort*)&a;
    #pragma unroll
    for (int j = 0; j < 8; ++j) o.s[j] = f2bf(bf2f(as[j]) * qv[qb + j]);
    return o.v;
}

__global__ __launch_bounds__(256, 4) void kA_attn(
    const float* __restrict__ emb_user,
    const float* __restrict__ emb_item,
    const float* __restrict__ emb_cate,
    const int* __restrict__ user,
    const int* __restrict__ items,
    const int* __restrict__ cates,
    const int* __restrict__ ii,
    const int* __restrict__ ic,
    const ushort* __restrict__ WcFrag,
    const ushort* __restrict__ WacF,
    const float* __restrict__ w23g,
    const float* __restrict__ c23g,
    ushort* __restrict__ feat)
{
    __shared__ __align__(16) ushort heb[4][64 * 56];   // he bf16 [64 rows][48+8pad]
    __shared__ __align__(16) float  qf[4][48];
    __shared__ __align__(16) float  uf[4][32];
    __shared__ __align__(16) float  qcl[4][64];
    __shared__ __align__(16) float  scl[4][52];
    __shared__ int    iml[4][52];
    __shared__ int    icl[4][52];

    const int t = threadIdx.x;
    const int w = t >> 6, l = t & 63;
    const int bn = blockIdx.x * 4 + w;
    const int col = l & 15, g = l >> 4;

    ushort* hb = &heb[w][0];
    const float* qv = &qf[w][0];

    // ---- P0: q, u, index gathers (all wave-private) ----
    if (l < 12) {
        int it_ = items[bn], ct = cates[bn];
        float4 v = (l < 8) ? ((const float4*)emb_item)[(size_t)it_ * 8 + l]
                           : ((const float4*)emb_cate)[(size_t)ct * 4 + (l - 8)];
        *(float4*)&qf[w][l * 4] = v;
    } else if (l >= 16 && l < 24) {
        int ur = user[bn];
        *(float4*)&uf[w][(l - 16) * 4] = ((const float4*)emb_user)[(size_t)ur * 8 + (l - 16)];
    }
    if (l < NL) {
        iml[w][l] = ii[(size_t)bn * NL + l];
        icl[w][l] = ic[(size_t)bn * NL + l];
    }
    wave_lds_fence();

    // ---- P1: he gather -> LDS bf16 (rows >= 50 left garbage: D-rows are independent) ----
    #pragma unroll
    for (int e0 = 0; e0 < 300; e0 += 64) {
        int e = e0 + l;
        if (e < 300) {
            int row = e / 6, c = e - row * 6;
            int k0 = c * 8;
            const float* src = (k0 < 32)
                ? emb_item + (size_t)iml[w][row] * 32 + k0
                : emb_cate + (size_t)icl[w][row] * 16 + (k0 - 32);
            float4 f0 = *(const float4*)src;
            float4 f1 = *(const float4*)(src + 4);
            union { short8 v; ushort s[8]; } o;
            o.s[0] = f2bf(f0.x); o.s[1] = f2bf(f0.y); o.s[2] = f2bf(f0.z); o.s[3] = f2bf(f0.w);
            o.s[4] = f2bf(f1.x); o.s[5] = f2bf(f1.y); o.s[6] = f2bf(f1.z); o.s[7] = f2bf(f1.w);
            *(short8*)&hb[row * 56 + c * 8] = o.v;
        }
    }
    wave_lds_fence();

    // ---- P2: qc = [q|1] @ WacF via MFMA (bias row folded at k=48) ----
    {
        short8 afq[2];
        #pragma unroll
        for (int ks = 0; ks < 2; ++ks) {
            union { short8 v; ushort s[8]; } a;
            a.v = short8{0,0,0,0,0,0,0,0};
            if (col == 0) {
                int k0 = ks * 32 + g * 8;
                if (k0 < 48) {
                    float4 x = *(const float4*)&qf[w][k0];
                    float4 y = *(const float4*)&qf[w][k0 + 4];
                    a.s[0] = f2bf(x.x); a.s[1] = f2bf(x.y); a.s[2] = f2bf(x.z); a.s[3] = f2bf(x.w);
                    a.s[4] = f2bf(y.x); a.s[5] = f2bf(y.y); a.s[6] = f2bf(y.z); a.s[7] = f2bf(y.w);
                } else if (k0 == 48) {
                    a.s[0] = 0x3F80;   // bf16(1.0) -> picks up b1 row
                }
            }
            afq[ks] = a.v;
        }
        f32x4 aq[4];
        #pragma unroll
        for (int nt = 0; nt < 4; ++nt) {
            aq[nt] = f32x4{0,0,0,0};
            #pragma unroll
            for (int ks = 0; ks < 2; ++ks) {
                short8 bq = *(const short8*)&WacF[((nt * 2 + ks) * 64 + l) * 8];
                aq[nt] = __builtin_amdgcn_mfma_f32_16x16x32_bf16(afq[ks], bq, aq[nt], 0, 0, 0);
            }
        }
        if (g == 0) {
            #pragma unroll
            for (int nt = 0; nt < 4; ++nt) qcl[w][nt * 16 + col] = aq[nt][0];
        }
    }

    // ---- P3: S = [he | he*q] @ Wcat via MFMA ----
    f32x4 acc[4][4];
    #pragma unroll
    for (int m = 0; m < 4; ++m)
        #pragma unroll
        for (int n = 0; n < 4; ++n) acc[m][n] = f32x4{0,0,0,0};

    #pragma unroll
    for (int ks = 0; ks < 3; ++ks) {
        short8 af[4];
        #pragma unroll
        for (int mt = 0; mt < 4; ++mt) {
            int row = mt * 16 + col;
            if (ks == 0)       af[mt] = lds8(hb, row, g);
            else if (ks == 1)  af[mt] = (g < 2) ? lds8(hb, row, 4 + g)
                                                : scale8(hb, qv, row, g - 2, (g - 2) * 8);
            else               af[mt] = scale8(hb, qv, row, 2 + g, 16 + g * 8);
        }
        #pragma unroll
        for (int nt = 0; nt < 4; ++nt) {
            short8 bf = *(const short8*)&WcFrag[((nt * 3 + ks) * 64 + l) * 8];
            #pragma unroll
            for (int mt = 0; mt < 4; ++mt)
                acc[mt][nt] = __builtin_amdgcn_mfma_f32_16x16x32_bf16(af[mt], bf, acc[mt][nt], 0, 0, 0);
        }
    }
    wave_lds_fence();   // qcl written (P2) before P4 reads

    // ---- P4: score = relu(S + qc) . w23 + c23, mask ----
    {
        float qcv[4], wv[4];
        #pragma unroll
        for (int nt = 0; nt < 4; ++nt) {
            qcv[nt] = qcl[w][nt * 16 + col];
            wv[nt]  = w23g[nt * 16 + col];
        }
        float c23 = c23g[0];
        #pragma unroll
        for (int mt = 0; mt < 4; ++mt) {
            #pragma unroll
            for (int i = 0; i < 4; ++i) {
                float s = fmaxf(acc[mt][0][i] + qcv[0], 0.f) * wv[0]
                        + fmaxf(acc[mt][1][i] + qcv[1], 0.f) * wv[1]
                        + fmaxf(acc[mt][2][i] + qcv[2], 0.f) * wv[2]
                        + fmaxf(acc[mt][3][i] + qcv[3], 0.f) * wv[3];
                s += __shfl_xor(s, 1, 16);
                s += __shfl_xor(s, 2, 16);
                s += __shfl_xor(s, 4, 16);
                s += __shfl_xor(s, 8, 16);
                int row = mt * 16 + g * 4 + i;
                if (col == 0 && row < NL)
                    scl[w][row] = (iml[w][row] == 0) ? 0.f : (s + c23);
            }
        }
    }
    wave_lds_fence();   // scl written before P5 reads

    // ---- P5: pooled + feat writes ----
    const size_t fb = (size_t)bn * 128;
    if (l < 48) {
        float p = 0.f;
        #pragma unroll
        for (int r4 = 0; r4 < 48; r4 += 4) {
            float4 sv = *(const float4*)&scl[w][r4];
            p = fmaf(sv.x, bf2f(hb[(r4 + 0) * 56 + l]), p);
            p = fmaf(sv.y, bf2f(hb[(r4 + 1) * 56 + l]), p);
            p = fmaf(sv.z, bf2f(hb[(r4 + 2) * 56 + l]), p);
            p = fmaf(sv.w, bf2f(hb[(r4 + 3) * 56 + l]), p);
        }
        float2 st = *(const float2*)&scl[w][48];
        p = fmaf(st.x, bf2f(hb[48 * 56 + l]), p);
        p = fmaf(st.y, bf2f(hb[49 * 56 + l]), p);
        feat[fb + 48 + l] = f2bf(p);
        feat[fb + l] = f2bf(qv[l]);
    }
    if (l < 32) feat[fb + 96 + l] = f2bf(uf[w][l]);
}

// ================= k2: MLP 128->200->80->1, pure MFMA, 1 wave = 16 rows =================
__global__ __launch_bounds__(64, 4) void k2_fc(
    const ushort* __restrict__ feat,
    const ushort* __restrict__ W1frag,
    const ushort* __restrict__ W2frag,
    const float* __restrict__ fb1, const float* __restrict__ fb2,
    const float* __restrict__ fw3, const float* __restrict__ fb3,
    const int* __restrict__ items,
    float* __restrict__ logits)
{
    __shared__ __align__(16) ushort x1s[16 * 256];  // [16 rows][224+pad] swizzled bf16

    const int l = threadIdx.x;
    const int r0 = blockIdx.x * 16;
    const int col = l & 15, g = l >> 4;

    // ---- layer 1: 13nt x 4ks MFMA, A from feat global ----
    short8 afr[4];
    #pragma unroll
    for (int ks = 0; ks < 4; ++ks)
        afr[ks] = *(const short8*)&feat[(size_t)(r0 + col) * 128 + ks * 32 + g * 8];

    f32x4 acc[13];
    #pragma unroll
    for (int nt = 0; nt < 13; ++nt) acc[nt] = f32x4{0,0,0,0};
    #pragma unroll
    for (int nt = 0; nt < 13; ++nt)
        #pragma unroll
        for (int ks = 0; ks < 4; ++ks) {
            short8 bf = *(const short8*)&W1frag[((nt * 4 + ks) * 64 + l) * 8];
            acc[nt] = __builtin_amdgcn_mfma_f32_16x16x32_bf16(afr[ks], bf, acc[nt], 0, 0, 0);
        }

    // zero pad chunks 26,27 (k 208..223) of x1
    if (l < 32) {
        int row = l >> 1, c = 26 + (l & 1);
        *(short8*)&x1s[row * 256 + ((c ^ (row & 7)) << 3)] = short8{0,0,0,0,0,0,0,0};
    }
    // relu + bias -> x1 LDS (bf16, XOR-swizzled chunks)
    #pragma unroll
    for (int nt = 0; nt < 13; ++nt) {
        int n = nt * 16 + col;
        float bias = (n < 200) ? fb1[n] : 0.f;
        #pragma unroll
        for (int i = 0; i < 4; ++i) {
            int row = g * 4 + i;
            float v = fmaxf(acc[nt][i] + bias, 0.f);
            int sw = (n >> 3) ^ (row & 7);
            x1s[row * 256 + sw * 8 + (n & 7)] = f2bf(v);
        }
    }
    wave_lds_fence();

    // ---- layer 2: 6nt x 7ks MFMA, A from x1s ----
    f32x4 acc2[6];
    #pragma unroll
    for (int nt = 0; nt < 6; ++nt) acc2[nt] = f32x4{0,0,0,0};
    #pragma unroll
    for (int ks = 0; ks < 7; ++ks) {
        int chunk = ks * 4 + g;
        short8 a = *(const short8*)&x1s[col * 256 + ((chunk ^ (col & 7)) << 3)];
        #pragma unroll
        for (int nt = 0; nt < 6; ++nt) {
            short8 bf = *(const short8*)&W2frag[((nt * 7 + ks) * 64 + l) * 8];
            acc2[nt] = __builtin_amdgcn_mfma_f32_16x16x32_bf16(a, bf, acc2[nt], 0, 0, 0);
        }
    }

    // ---- layer 3: dot over 80 + sigmoid + mask ----
    {
        float s[4] = {0.f, 0.f, 0.f, 0.f};
        #pragma unroll
        for (int nt = 0; nt < 5; ++nt) {
            int n = nt * 16 + col;
            float b2v = fb2[n], w3v = fw3[n];
            #pragma unroll
            for (int i = 0; i < 4; ++i)
                s[i] = fmaf(fmaxf(acc2[nt][i] + b2v, 0.f), w3v, s[i]);
        }
        #pragma unroll
        for (int i = 0; i < 4; ++i) {
            s[i] += __shfl_xor(s[i], 1, 16);
            s[i] += __shfl_xor(s[i], 2, 16);
            s[i] += __shfl_xor(s[i], 4, 16);
            s[i] += __shfl_xor(s[i], 8, 16);
        }
        if (col == 0) {
            float b3 = fb3[0];
            #pragma unroll
            for (int i = 0; i < 4; ++i) {
                int row = r0 + g * 4 + i;
                float lg = (items[row] == 0) ? -INFINITY
                                             : 1.f / (1.f + __expf(-(s[i] + b3)));
                logits[row] = lg;
            }
        }
    }
}

// ================= k3: masked softmax =================
__global__ __launch_bounds__(256) void k3_softmax(
    const float* __restrict__ logits, float* __restrict__ out)
{
    const int b = blockIdx.x, t = threadIdx.x;
    __shared__ float red[4];
    float v = logits[b * 256 + t];
    float m = v;
    #pragma unroll
    for (int off = 32; off; off >>= 1) m = fmaxf(m, __shfl_xor(m, off, 64));
    if ((t & 63) == 0) red[t >> 6] = m;
    __syncthreads();
    float mx = fmaxf(fmaxf(red[0], red[1]), fmaxf(red[2], red[3]));
    float e = __expf(v - mx);
    float s = e;
    #pragma unroll
    for (int off = 32; off; off >>= 1) s += __shfl_xor(s, off, 64);
    __syncthreads();
    if ((t & 63) == 0) red[t >> 6] = s;
    __syncthreads();
    float tot = red[0] + red[1] + red[2] + red[3];
    out[b * 256 + t] = e / tot;
}

extern "C" void kernel_launch(void* const* d_in, const int* in_sizes, int n_in,
                              void* d_out, int out_size, void* d_ws, size_t ws_size,
                              hipStream_t stream)
{
    const float* emb_user = (const float*)d_in[0];
    const float* emb_item = (const float*)d_in[1];
    const float* emb_cate = (const float*)d_in[2];
    const float* aw1 = (const float*)d_in[3];
    const float* ab1 = (const float*)d_in[4];
    const float* aw2 = (const float*)d_in[5];
    const float* ab2 = (const float*)d_in[6];
    const float* aw3 = (const float*)d_in[7];
    const float* ab3 = (const float*)d_in[8];
    const float* fw1 = (const float*)d_in[9];
    const float* fb1 = (const float*)d_in[10];
    const float* fw2 = (const float*)d_in[11];
    const float* fb2 = (const float*)d_in[12];
    const float* fw3 = (const float*)d_in[13];
    const float* fb3 = (const float*)d_in[14];
    const int* user  = (const int*)d_in[15];
    const int* items = (const int*)d_in[16];
    const int* cates = (const int*)d_in[17];
    const int* ii    = (const int*)d_in[18];
    const int* ic    = (const int*)d_in[19];

    char* ws = (char*)d_ws;
    ushort* feat   = (ushort*)(ws + WS_FEAT);
    float*  logits = (float*) (ws + WS_LOGITS);
    ushort* W1frag = (ushort*)(ws + WS_W1FRAG);
    ushort* W2frag = (ushort*)(ws + WS_W2FRAG);
    ushort* WcFrag = (ushort*)(ws + WS_WCFRAG);
    ushort* WacF   = (ushort*)(ws + WS_WACF);
    float*  w23    = (float*) (ws + WS_W23);
    float*  c23    = (float*) (ws + WS_C23);

    k0_prep<<<229, 256, 0, stream>>>(aw1, ab1, ab2, aw2, aw3, ab3, fw1, fw2,
                                     W1frag, W2frag, WcFrag, WacF, w23, c23);
    kA_attn<<<BN_TOT / 4, 256, 0, stream>>>(emb_user, emb_item, emb_cate,
                                            user, items, cates, ii, ic,
                                            WcFrag, WacF, w23, c23, feat);
    k2_fc<<<BN_TOT / 16, 64, 0, stream>>>(feat, W1frag, W2frag,
                                          fb1, fb2, fw3, fb3, items, logits);
    k3_softmax<<<32, 256, 0, stream>>>(logits, (float*)d_out);
}